// Round 9
// baseline (1626.897 us; speedup 1.0000x reference)
//
#include <hip/hip_runtime.h>
#include <stdint.h>

#define NB 512
#define NT 20
#define NH 256
#define NO 128
#define MUO_OFF (2*NB*NT*NO)
#define VARO_OFF (MUO_OFF + NB*NT*NH)

// ===== LEDGER =====
//  R6: PASS 6587us f32 serial. R7: PASS 1557us f32 tiled. R8: FAIL absmax 1.25 —
//      bf16 drift through 19-step recurrence (layout verified OK: error << 19).
//  R9 (this): split-bf16 hi/lo emulated-f32 MFMA (3 mfma/tile: ahi*whi + ahi*wlo
//      + alo*whi), BN+split once per A-tile into LDS, hstate split in sdht,
//      mu/sd tables aliased onto out buffer. 6 launches/step.
//      Predict: absmax ~0.03-0.06, dur 450-700us.
// ==================

typedef __attribute__((ext_vector_type(8))) short short8v;
typedef __attribute__((ext_vector_type(4))) float f32x4;
typedef unsigned short ushort_t;

// ws float offsets
#define O_PS   0
#define O_A1   (O_PS + NB*NH)
#define O_A2   (O_A1 + 512*512)
#define O_E1   (O_A2 + 512*512)
#define O_P1   (O_E1 + 512*512)
#define O_P2   (O_P1 + 512*32*2)
#define O_PSD  (O_P2 + 512*32*2)
#define O_PE   (O_PSD + 256*32*2)
#define O_PIS  (O_PE + 512*32*2)
#define O_USH  (O_PIS + NT*NB)
// ushort offsets within U
#define U_WT1H 0
#define U_WT1L 131072
#define U_WT2H 262144
#define U_WT2L 557056
#define U_WMSH 851968
#define U_WMSL 1114112
#define U_WE1H 1376256
#define U_WE1L 1507328
#define U_WESH 1638400
#define U_WESL 1769472
#define U_HHI  1900544
#define U_HLO  2031616

__host__ __device__ __forceinline__ void tf2x32(uint32_t k0, uint32_t k1,
                                                uint32_t x0, uint32_t x1,
                                                uint32_t& o0, uint32_t& o1)
{
  uint32_t k2 = k0 ^ k1 ^ 0x1BD11BDAu;
  x0 += k0; x1 += k1;
#define TF_R(r) x0 += x1; x1 = (x1 << (r)) | (x1 >> (32 - (r))); x1 ^= x0;
  TF_R(13) TF_R(15) TF_R(26) TF_R(6)
  x0 += k1; x1 += k2 + 1u;
  TF_R(17) TF_R(29) TF_R(16) TF_R(24)
  x0 += k2; x1 += k0 + 2u;
  TF_R(13) TF_R(15) TF_R(26) TF_R(6)
  x0 += k0; x1 += k1 + 3u;
  TF_R(17) TF_R(29) TF_R(16) TF_R(24)
  x0 += k1; x1 += k2 + 4u;
  TF_R(13) TF_R(15) TF_R(26) TF_R(6)
  x0 += k2; x1 += k0 + 5u;
#undef TF_R
  o0 = x0; o1 = x1;
}

__device__ __forceinline__ uint32_t rbits(uint32_t ka, uint32_t kb, uint32_t i)
{
  uint32_t o0, o1;
  tf2x32(ka, kb, 0u, i, o0, o1);
  return o0 ^ o1;
}

__device__ __forceinline__ float erfinv_xla(float x)
{
  float w = -log1pf(-__fmul_rn(x, x));
  float p;
  if (w < 5.0f) {
    w = __fsub_rn(w, 2.5f);
    p = 2.81022636e-08f;
    p = __fadd_rn( 3.43273939e-07f, __fmul_rn(p, w));
    p = __fadd_rn(-3.5233877e-06f,  __fmul_rn(p, w));
    p = __fadd_rn(-4.39150654e-06f, __fmul_rn(p, w));
    p = __fadd_rn( 0.00021858087f,  __fmul_rn(p, w));
    p = __fadd_rn(-0.00125372503f,  __fmul_rn(p, w));
    p = __fadd_rn(-0.00417768164f,  __fmul_rn(p, w));
    p = __fadd_rn( 0.246640727f,    __fmul_rn(p, w));
    p = __fadd_rn( 1.50140941f,     __fmul_rn(p, w));
  } else {
    w = __fsub_rn(sqrtf(w), 3.0f);
    p = -0.000200214257f;
    p = __fadd_rn( 0.000100950558f, __fmul_rn(p, w));
    p = __fadd_rn( 0.00134934322f,  __fmul_rn(p, w));
    p = __fadd_rn(-0.00367342844f,  __fmul_rn(p, w));
    p = __fadd_rn( 0.00573950773f,  __fmul_rn(p, w));
    p = __fadd_rn(-0.0076224613f,   __fmul_rn(p, w));
    p = __fadd_rn( 0.00943887047f,  __fmul_rn(p, w));
    p = __fadd_rn( 1.00167406f,     __fmul_rn(p, w));
    p = __fadd_rn( 2.83297682f,     __fmul_rn(p, w));
  }
  return __fmul_rn(p, x);
}

__device__ __forceinline__ float jax_normal(uint32_t bits)
{
  float f = __fsub_rn(__uint_as_float((bits >> 9) | 0x3F800000u), 1.0f);
  const float lo = -0.99999994f;
  float u = __fadd_rn(__fmul_rn(f, 2.0f), lo);
  u = fmaxf(lo, u);
  return __fmul_rn(1.41421356f, erfinv_xla(u));
}

__device__ __forceinline__ ushort_t f2bf(float x)  // round-nearest-even
{
  uint32_t u = __float_as_uint(x);
  return (ushort_t)((u + 0x7FFFu + ((u >> 16) & 1u)) >> 16);
}

// split x into hi (trunc bf16) + lo (rn bf16 of residual)
__device__ __forceinline__ void bfsplit(float x, ushort_t& hi, ushort_t& lo)
{
  uint32_t u = __float_as_uint(x);
  hi = (ushort_t)(u >> 16);
  float r = x - __uint_as_float(u & 0xFFFF0000u);
  lo = f2bf(r);
}

// ---------------- init ----------------

__global__ void k_init_x(const float* __restrict__ x, float* __restrict__ out)
{
  int i = blockIdx.x * blockDim.x + threadIdx.x;
  const int total = NB * NT * NO;
  if (i >= total) return;
  float v = x[i];
  out[total + i] = v;
  if ((i % (NT * NO)) < NO) out[i] = v;
}

__global__ void k_init_h(const float* __restrict__ mu0, const float* __restrict__ var0,
                         const float* __restrict__ h0,
                         float* __restrict__ out,
                         ushort_t* __restrict__ hhi, ushort_t* __restrict__ hlo)
{
  int i = blockIdx.x * blockDim.x + threadIdx.x;
  if (i >= NB * NH) return;
  int b = i >> 8, h = i & 255;
  out[MUO_OFF  + (b * NT) * NH + h] = mu0[h];
  out[VARO_OFF + (b * NT) * NH + h] = var0[h];
  ushort_t hi, lo;
  bfsplit(h0[h], hi, lo);
  hhi[i] = hi; hlo[i] = lo;
}

__global__ void k_conv(const float* __restrict__ tW1, const float* __restrict__ tW2,
                       const float* __restrict__ tWm, const float* __restrict__ tWs,
                       const float* __restrict__ eW1, const float* __restrict__ eWm,
                       const float* __restrict__ eWs, ushort_t* __restrict__ U)
{
  int i = blockIdx.x * blockDim.x + threadIdx.x;
  if (i >= 950272) return;
  float v; int ho, lo_;
  if (i < 131072) { v = tW1[i]; ho = U_WT1H + i; lo_ = U_WT1L + i; }
  else if (i < 425984) { int j = i - 131072; v = tW2[j]; ho = U_WT2H + j; lo_ = U_WT2L + j; }
  else if (i < 688128) { int j = i - 425984; int n = j >> 9, k = j & 511;
    v = (n < 256) ? tWm[n * 512 + k] : tWs[(n - 256) * 512 + k];
    ho = U_WMSH + j; lo_ = U_WMSL + j; }
  else if (i < 819200) { int j = i - 688128; v = eW1[j]; ho = U_WE1H + j; lo_ = U_WE1L + j; }
  else { int j = i - 819200; int n = j >> 9, k = j & 511;
    v = (n < 128) ? eWm[n * 512 + k] : eWs[(n - 128) * 512 + k];
    ho = U_WESH + j; lo_ = U_WESL + j; }
  ushort_t h, l;
  bfsplit(v, h, l);
  U[ho] = h; U[lo_] = l;
}

__global__ void k_pisall(const float* __restrict__ h_gru, int* __restrict__ pisA)
{
  int b = blockIdx.x;
  int t = blockIdx.y + 1;
  int l = threadIdx.x;
  uint32_t kt0, kt1, k1a, k1b;
  tf2x32(0u, 42u, 0u, (uint32_t)t, kt0, kt1);
  tf2x32(kt0, kt1, 0u, 0u, k1a, k1b);
  float v = -__builtin_inff();
  int idx = 0x7FFFFFFF;
  if (l < t) {
    const float* hq = h_gru + (b * NT + t) * NH;
    const float* hu = h_gru + (b * NT + l) * NH;
    float d = 0.0f;
    for (int h = 0; h < NH; ++h) d += hq[h] * hu[h];
    float logit = d * 0.0625f;
    uint32_t bits = rbits(k1a, k1b, (uint32_t)(b * t + l));
    float f = __fsub_rn(__uint_as_float((bits >> 9) | 0x3F800000u), 1.0f);
    const float tinyf = 1.1754943508222875e-38f;
    float u = fmaxf(tinyf, __fadd_rn(f, tinyf));
    float gmb = -logf(-logf(u));
    v = gmb + logit;
    idx = l;
  }
  for (int off = 32; off; off >>= 1) {
    float ov = __shfl_xor(v, off);
    int oi = __shfl_xor(idx, off);
    if (ov > v || (ov == v && oi < idx)) { v = ov; idx = oi; }
  }
  if (l == 0) pisA[t * NB + b] = idx;
}

// ---------------- split-bf16 MFMA GEMMs ----------------
// C[m][n] = sum_k bn(A)[m][k]*W[n][k], emulated f32 via hi/lo bf16 split.
// A f32 (stride 512; CONC: k>=512 from Sf stride 64 raw). BN coeffs from partIn.
// Tile: block = (n-group 64) x (m-group 16); 4 waves share the A-tile in LDS.
// EPI 0: relu -> Of32 (stride 512) + partials. EPI 1: n<256 mu->out; else elu->ps+partials.
template<int K, int CONC, int EPI>
__global__ __launch_bounds__(256) void k_mfs(
    const float* __restrict__ Af, const float* __restrict__ Sf,
    const float* __restrict__ partIn, const float* __restrict__ g,
    const float* __restrict__ be,
    const ushort_t* __restrict__ Whi, const ushort_t* __restrict__ Wlo,
    const float* __restrict__ b0, const float* __restrict__ b1,
    float* __restrict__ Of32, float* __restrict__ partOut,
    float* __restrict__ ps, float* __restrict__ outp, int t)
{
  constexpr int KP = K + 8;
  constexpr int NS = K / 32;
  const int tid = threadIdx.x;
  const int w = tid >> 6, l = tid & 63;
  const int mt = blockIdx.y, M0 = mt * 16;
  const int N0 = blockIdx.x * 64 + w * 16;
  const int lm = l & 15, lk = l >> 4;

  __shared__ ushort_t Ahi[16][KP];
  __shared__ ushort_t Alo[16][KP];
  __shared__ float2 scsh[512];

  for (int c = tid; c < 512; c += 256) {
    const float2* pp = (const float2*)partIn + c * 32;
    float s = 0.0f, q = 0.0f;
    #pragma unroll
    for (int m = 0; m < 32; ++m) { float2 v = pp[m]; s += v.x; q += v.y; }
    float mn  = s * (1.0f / 512.0f);
    float var = q * (1.0f / 512.0f) - mn * mn;
    float inv = 1.0f / sqrtf(var + 1e-5f);
    float sc  = inv * g[c];
    scsh[c] = make_float2(sc, be[c] - mn * sc);
  }
  __syncthreads();

  // BN + split A tile into LDS (shared by all 4 waves)
  for (int r = 0; r < 16; ++r) {
    for (int c = tid; c < K; c += 256) {
      float v;
      if constexpr (CONC) {
        if (c < 512) { float2 ss = scsh[c];
          v = __builtin_fmaf(Af[(M0 + r) * 512 + c], ss.x, ss.y); }
        else v = Sf[(M0 + r) * 64 + (c - 512)];
      } else {
        float2 ss = scsh[c];
        v = __builtin_fmaf(Af[(M0 + r) * K + c], ss.x, ss.y);
      }
      ushort_t hi, lo;
      bfsplit(v, hi, lo);
      Ahi[r][c] = hi; Alo[r][c] = lo;
    }
  }
  __syncthreads();

  const ushort_t* bhrow = Whi + (N0 + lm) * K;
  const ushort_t* blrow = Wlo + (N0 + lm) * K;
  f32x4 acc = {0.0f, 0.0f, 0.0f, 0.0f};
  #pragma unroll
  for (int ks = 0; ks < NS; ++ks) {
    const int kb = ks * 32 + lk * 8;
    short8v ah = *reinterpret_cast<const short8v*>(&Ahi[lm][kb]);
    short8v al = *reinterpret_cast<const short8v*>(&Alo[lm][kb]);
    short8v wh = *reinterpret_cast<const short8v*>(bhrow + kb);
    short8v wl = *reinterpret_cast<const short8v*>(blrow + kb);
    acc = __builtin_amdgcn_mfma_f32_16x16x32_bf16(ah, wh, acc, 0, 0, 0);
    acc = __builtin_amdgcn_mfma_f32_16x16x32_bf16(ah, wl, acc, 0, 0, 0);
    acc = __builtin_amdgcn_mfma_f32_16x16x32_bf16(al, wh, acc, 0, 0, 0);
  }

  const int n = N0 + lm;
  if constexpr (EPI == 0) {
    float bias = b0[n];
    float s = 0.0f, q = 0.0f;
    #pragma unroll
    for (int j = 0; j < 4; ++j) {
      float x = fmaxf(acc[j] + bias, 0.0f);
      s += x; q += x * x;
      Of32[(M0 + lk * 4 + j) * 512 + n] = x;
    }
    s += __shfl_xor(s, 16); s += __shfl_xor(s, 32);
    q += __shfl_xor(q, 16); q += __shfl_xor(q, 32);
    if (l < 16) ((float2*)partOut)[n * 32 + mt] = make_float2(s, q);
  } else {
    if (N0 < 256) {
      float bias = b0[n];
      #pragma unroll
      for (int j = 0; j < 4; ++j) {
        float x = acc[j] + bias;
        int m = M0 + lk * 4 + j;
        outp[MUO_OFF + (m * NT + t) * NH + n] = x;
      }
    } else {
      float bias = b1[n - 256];
      float s = 0.0f, q = 0.0f;
      #pragma unroll
      for (int j = 0; j < 4; ++j) {
        float x = acc[j] + bias;
        x = (x > 0.0f ? x : expm1f(x)) + 1.0f + 1e-12f;
        s += x; q += x * x;
        ps[(M0 + lk * 4 + j) * NH + (n - 256)] = x;
      }
      s += __shfl_xor(s, 16); s += __shfl_xor(s, 32);
      q += __shfl_xor(q, 16); q += __shfl_xor(q, 32);
      if (l < 16) ((float2*)partOut)[(n - 256) * 32 + mt] = make_float2(s, q);
    }
  }
}

// G1/G4: A = hstate pre-split (global hi/lo, K=256), no BN. relu epi + partials.
__global__ __launch_bounds__(256) void k_mfh(
    const ushort_t* __restrict__ Ahi_g, const ushort_t* __restrict__ Alo_g,
    const ushort_t* __restrict__ Whi, const ushort_t* __restrict__ Wlo,
    const float* __restrict__ b0,
    float* __restrict__ Of32, float* __restrict__ partOut)
{
  const int tid = threadIdx.x;
  const int w = tid >> 6, l = tid & 63;
  const int mt = blockIdx.y, M0 = mt * 16;
  const int N0 = blockIdx.x * 64 + w * 16;
  const int lm = l & 15, lk = l >> 4;

  const ushort_t* ah_r = Ahi_g + (M0 + lm) * 256;
  const ushort_t* al_r = Alo_g + (M0 + lm) * 256;
  const ushort_t* wh_r = Whi + (N0 + lm) * 256;
  const ushort_t* wl_r = Wlo + (N0 + lm) * 256;
  f32x4 acc = {0.0f, 0.0f, 0.0f, 0.0f};
  #pragma unroll
  for (int ks = 0; ks < 8; ++ks) {
    const int kb = ks * 32 + lk * 8;
    short8v ah = *reinterpret_cast<const short8v*>(ah_r + kb);
    short8v al = *reinterpret_cast<const short8v*>(al_r + kb);
    short8v wh = *reinterpret_cast<const short8v*>(wh_r + kb);
    short8v wl = *reinterpret_cast<const short8v*>(wl_r + kb);
    acc = __builtin_amdgcn_mfma_f32_16x16x32_bf16(ah, wh, acc, 0, 0, 0);
    acc = __builtin_amdgcn_mfma_f32_16x16x32_bf16(ah, wl, acc, 0, 0, 0);
    acc = __builtin_amdgcn_mfma_f32_16x16x32_bf16(al, wh, acc, 0, 0, 0);
  }

  const int n = N0 + lm;
  float bias = b0[n];
  float s = 0.0f, q = 0.0f;
  #pragma unroll
  for (int j = 0; j < 4; ++j) {
    float x = fmaxf(acc[j] + bias, 0.0f);
    s += x; q += x * x;
    Of32[(M0 + lk * 4 + j) * 512 + n] = x;
  }
  s += __shfl_xor(s, 16); s += __shfl_xor(s, 32);
  q += __shfl_xor(q, 16); q += __shfl_xor(q, 32);
  if (l < 16) ((float2*)partOut)[n * 32 + mt] = make_float2(s, q);
}

// sd finalize + BN + ht sample; mu/sd gathered from out buffer (slot p+1)
__global__ __launch_bounds__(256) void k_sdht(
    const float* __restrict__ partS, const float* __restrict__ psv,
    const float* __restrict__ gs, const float* __restrict__ bes,
    const int* __restrict__ pisA,
    ushort_t* __restrict__ hhi, ushort_t* __restrict__ hlo,
    uint32_t k2a, uint32_t k2b, float* __restrict__ outp, int t)
{
  int b = blockIdx.x, c = threadIdx.x;
  const float2* pp = (const float2*)partS + c * 32;
  float s = 0.0f, q = 0.0f;
  #pragma unroll
  for (int m = 0; m < 32; ++m) { float2 v = pp[m]; s += v.x; q += v.y; }
  float mn  = s * (1.0f / 512.0f);
  float var = q * (1.0f / 512.0f) - mn * mn;
  float inv = 1.0f / sqrtf(var + 1e-5f);
  float sc  = inv * gs[c];
  float sh  = bes[c] - mn * sc;
  float v = psv[b * NH + c] * sc + sh;
  outp[VARO_OFF + (b * NT + t) * NH + c] = v;
  int p = pisA[t * NB + b];
  float mu = outp[MUO_OFF + (b * NT + p + 1) * NH + c];
  float sd = (p == t - 1) ? v : outp[VARO_OFF + (b * NT + p + 1) * NH + c];
  float z = jax_normal(rbits(k2a, k2b, (uint32_t)(b * NH + c)));
  float ht = __fadd_rn(mu, __fmul_rn(sd, z));
  ushort_t hi, lo;
  bfsplit(ht, hi, lo);
  hhi[b * NH + c] = hi; hlo[b * NH + c] = lo;
}

// emission heads + sample. grid (4, 32). waves 0/1: mean; 2/3: std.
__global__ __launch_bounds__(256) void k_g5(
    const float* __restrict__ Ef, const ushort_t* __restrict__ Whi,
    const ushort_t* __restrict__ Wlo,
    const float* __restrict__ partIn, const float* __restrict__ g,
    const float* __restrict__ be,
    const float* __restrict__ bm, const float* __restrict__ bs,
    uint32_t k3a, uint32_t k3b, float* __restrict__ outp, int t)
{
  constexpr int K = 512, KP = 520;
  const int tid = threadIdx.x;
  const int w = tid >> 6, l = tid & 63;
  const int mt = blockIdx.y, jg = blockIdx.x;
  const int M0 = mt * 16;
  const int lm = l & 15, lk = l >> 4;
  const bool isStd = (w >= 2);
  const int jl0 = (w & 1) * 16;
  const int N0 = (isStd ? 128 : 0) + jg * 32 + jl0;

  __shared__ ushort_t Ahi[16][KP];
  __shared__ ushort_t Alo[16][KP];
  __shared__ float2 scsh[512];
  __shared__ float mean_s[16][32];
  __shared__ float std_s[16][32];

  for (int c = tid; c < 512; c += 256) {
    const float2* pp = (const float2*)partIn + c * 32;
    float s = 0.0f, q = 0.0f;
    #pragma unroll
    for (int m = 0; m < 32; ++m) { float2 v = pp[m]; s += v.x; q += v.y; }
    float mn  = s * (1.0f / 512.0f);
    float var = q * (1.0f / 512.0f) - mn * mn;
    float inv = 1.0f / sqrtf(var + 1e-5f);
    float sc  = inv * g[c];
    scsh[c] = make_float2(sc, be[c] - mn * sc);
  }
  __syncthreads();

  for (int r = 0; r < 16; ++r) {
    for (int c = tid; c < K; c += 256) {
      float2 ss = scsh[c];
      float v = __builtin_fmaf(Ef[(M0 + r) * 512 + c], ss.x, ss.y);
      ushort_t hi, lo;
      bfsplit(v, hi, lo);
      Ahi[r][c] = hi; Alo[r][c] = lo;
    }
  }
  __syncthreads();

  const ushort_t* bhrow = Whi + (N0 + lm) * K;
  const ushort_t* blrow = Wlo + (N0 + lm) * K;
  f32x4 acc = {0.0f, 0.0f, 0.0f, 0.0f};
  #pragma unroll
  for (int ks = 0; ks < 16; ++ks) {
    const int kb = ks * 32 + lk * 8;
    short8v ah = *reinterpret_cast<const short8v*>(&Ahi[lm][kb]);
    short8v al = *reinterpret_cast<const short8v*>(&Alo[lm][kb]);
    short8v wh = *reinterpret_cast<const short8v*>(bhrow + kb);
    short8v wl = *reinterpret_cast<const short8v*>(blrow + kb);
    acc = __builtin_amdgcn_mfma_f32_16x16x32_bf16(ah, wh, acc, 0, 0, 0);
    acc = __builtin_amdgcn_mfma_f32_16x16x32_bf16(ah, wl, acc, 0, 0, 0);
    acc = __builtin_amdgcn_mfma_f32_16x16x32_bf16(al, wh, acc, 0, 0, 0);
  }

  const int n = N0 + lm;
  float bias = isStd ? bs[n - 128] : bm[n];
  #pragma unroll
  for (int j = 0; j < 4; ++j) {
    float x = acc[j] + bias;
    if (isStd) x = (x > 0.0f ? x : expm1f(x)) + 1.0f + 1e-12f;
    int r = lk * 4 + j, jl = jl0 + lm;
    if (isStd) std_s[r][jl] = x; else mean_s[r][jl] = x;
  }
  __syncthreads();

  for (int e = tid; e < 512; e += 256) {
    int r = e >> 5, jl = e & 31;
    int bb = M0 + r, j = jg * 32 + jl;
    float z = jax_normal(rbits(k3a, k3b, (uint32_t)(bb * NO + j)));
    outp[(bb * NT + t) * NO + j] = __fadd_rn(mean_s[r][jl], __fmul_rn(std_s[r][jl], z));
  }
}

// ---------------- host ----------------

extern "C" void kernel_launch(void* const* d_in, const int* in_sizes, int n_in,
                              void* d_out, int out_size, void* d_ws, size_t ws_size,
                              hipStream_t stream)
{
  const float* x     = (const float*)d_in[0];
  const float* s     = (const float*)d_in[1];
  const float* h_gru = (const float*)d_in[2];
  const float* mu0   = (const float*)d_in[3];
  const float* var0  = (const float*)d_in[4];
  const float* h0    = (const float*)d_in[5];
  const float* tW1   = (const float*)d_in[6];
  const float* tb1   = (const float*)d_in[7];
  const float* tg1   = (const float*)d_in[8];
  const float* tbe1  = (const float*)d_in[9];
  const float* tW2   = (const float*)d_in[10];
  const float* tb2   = (const float*)d_in[11];
  const float* tg2   = (const float*)d_in[12];
  const float* tbe2  = (const float*)d_in[13];
  const float* tWm   = (const float*)d_in[14];
  const float* tbm   = (const float*)d_in[15];
  const float* tWs   = (const float*)d_in[16];
  const float* tbs   = (const float*)d_in[17];
  const float* tgs   = (const float*)d_in[18];
  const float* tbes  = (const float*)d_in[19];
  const float* eW1   = (const float*)d_in[20];
  const float* eb1   = (const float*)d_in[21];
  const float* eg1   = (const float*)d_in[22];
  const float* ebe1  = (const float*)d_in[23];
  const float* eWm   = (const float*)d_in[24];
  const float* ebm   = (const float*)d_in[25];
  const float* eWs   = (const float*)d_in[26];
  const float* ebs   = (const float*)d_in[27];

  float* out = (float*)d_out;
  float* ws  = (float*)d_ws;

  float* psf   = ws + O_PS;
  float* a1f   = ws + O_A1;
  float* a2f   = ws + O_A2;
  float* e1f   = ws + O_E1;
  float* part1 = ws + O_P1;
  float* part2 = ws + O_P2;
  float* partS = ws + O_PSD;
  float* partE = ws + O_PE;
  int*   pisA  = (int*)(ws + O_PIS);
  ushort_t* U  = (ushort_t*)(ws + O_USH);
  ushort_t* hhi = U + U_HHI;
  ushort_t* hlo = U + U_HLO;

  k_init_x<<<(NB * NT * NO + 255) / 256, 256, 0, stream>>>(x, out);
  k_init_h<<<(NB * NH + 255) / 256, 256, 0, stream>>>(mu0, var0, h0, out, hhi, hlo);
  k_conv<<<(950272 + 255) / 256, 256, 0, stream>>>(tW1, tW2, tWm, tWs, eW1, eWm, eWs, U);
  k_pisall<<<dim3(NB, NT - 1), 64, 0, stream>>>(h_gru, pisA);

  for (int t = 1; t < NT; ++t) {
    uint32_t kt0, kt1, k2a, k2b, k3a, k3b;
    tf2x32(0u, 42u, 0u, (uint32_t)t, kt0, kt1);
    tf2x32(kt0, kt1, 0u, 1u, k2a, k2b);
    tf2x32(kt0, kt1, 0u, 2u, k3a, k3b);

    // G1: a1 = relu(h . tW1^T + tb1)
    k_mfh<<<dim3(8, 32), 256, 0, stream>>>(
        hhi, hlo, U + U_WT1H, U + U_WT1L, tb1, a1f, part1);
    // G2: a2 = relu([bn(a1)|s] . tW2^T + tb2)
    k_mfs<576, 1, 0><<<dim3(8, 32), 256, 0, stream>>>(
        a1f, s, part1, tg1, tbe1, U + U_WT2H, U + U_WT2L, tb2, nullptr,
        a2f, part2, nullptr, nullptr, t);
    // G3: mu -> out; sd-raw -> ps (+ partials)
    k_mfs<512, 0, 1><<<dim3(8, 32), 256, 0, stream>>>(
        a2f, nullptr, part2, tg2, tbe2, U + U_WMSH, U + U_WMSL, tbm, tbs,
        nullptr, partS, psf, out, t);
    // sd finalize + ht sample (+ hstate split)
    k_sdht<<<NB, 256, 0, stream>>>(partS, psf, tgs, tbes, pisA,
                                   hhi, hlo, k2a, k2b, out, t);
    // G4: e1 = relu(h . eW1^T + eb1)
    k_mfh<<<dim3(8, 32), 256, 0, stream>>>(
        hhi, hlo, U + U_WE1H, U + U_WE1L, eb1, e1f, partE);
    // G5: emission heads + sample
    k_g5<<<dim3(4, 32), 256, 0, stream>>>(
        e1f, U + U_WESH, U + U_WESL, partE, eg1, ebe1,
        ebm, ebs, k3a, k3b, out, t);
  }
}